// Round 1
// baseline (2045.133 us; speedup 1.0000x reference)
//
#include <hip/hip_runtime.h>
#include <math.h>

#define BB 256
#define TT 2048
#define VOCAB 7
#define EMBD 20
#define HID 128
#define OUTD 6
#define G4 (4 * HID) /* 512 */
#define CHUNK 64
#define NCHUNK (TT / CHUNK)

// Single-instruction fast ops (ISA-guaranteed on gfx950, ~1 ULP)
__device__ __forceinline__ float v_exp2(float x) {
    float r; asm("v_exp_f32 %0, %1" : "=v"(r) : "v"(x)); return r;
}
__device__ __forceinline__ float v_rcp(float x) {
    float r; asm("v_rcp_f32 %0, %1" : "=v"(r) : "v"(x)); return r;
}
__device__ __forceinline__ float sigmoid_f(float x) {
    return v_rcp(1.0f + v_exp2(-1.44269504f * x));
}
__device__ __forceinline__ float tanh_f(float x) {
    float ax = fabsf(x);
    float t = v_exp2(-2.88539008f * ax);          // exp(-2|x|)
    float r = (1.0f - t) * v_rcp(1.0f + t);
    return __builtin_copysignf(r, x);
}

// One block per batch element; persistent over all T steps.
// Thread g owns gate row g: W_hh[g, 0:128] in 128 VGPRs.
__global__ __launch_bounds__(512, 2) void lstm_persist(
    const int* __restrict__ inputs, const float* __restrict__ c0,
    const float* __restrict__ W_ih, const float* __restrict__ W_hh,
    const float* __restrict__ b_ih, const float* __restrict__ b_hh,
    const float* __restrict__ W_fc, const float* __restrict__ b_fc,
    const float* __restrict__ emb, float* __restrict__ out)
{
    __shared__ float gtab[VOCAB][G4];      // 14 KB: per-token gate bias table
    __shared__ float h_hist[CHUNK][HID];   // 32 KB: h ring buffer (one chunk)
    __shared__ float gact[G4];             //  2 KB: activated gates this step
    __shared__ int   toks[CHUNK];          // 256 B

    const int tid = threadIdx.x;
    const int b   = blockIdx.x;
    const int g   = tid;          // gate row 0..511
    const int j   = tid & (HID - 1); // hidden unit this thread updates (replicated x4)
    const int lane = tid & 63;
    const int wave = tid >> 6;

    // ---- load W_hh row g into registers (128 VGPRs) ----
    float w[HID];
    {
        const float4* wr = (const float4*)(W_hh + (size_t)g * HID);
        #pragma unroll
        for (int k = 0; k < HID / 4; ++k) {
            float4 v = wr[k];
            w[4 * k + 0] = v.x; w[4 * k + 1] = v.y;
            w[4 * k + 2] = v.z; w[4 * k + 3] = v.w;
        }
    }

    // ---- build token->gate-preact table: gtab[v][g] = W_ih[g,:]·emb[v,:] + b_ih[g] + b_hh[g]
    {
        float wih[EMBD];
        #pragma unroll
        for (int e = 0; e < EMBD; ++e) wih[e] = W_ih[g * EMBD + e];
        float bb = b_ih[g] + b_hh[g];
        #pragma unroll
        for (int v = 0; v < VOCAB; ++v) {
            float a = bb;
            #pragma unroll
            for (int e = 0; e < EMBD; ++e) a += wih[e] * emb[v * EMBD + e];
            gtab[v][g] = a;
        }
    }

    // ---- state ----
    float c = c0[b * HID + j];              // replicated across the 4 gate groups
    if (tid < HID) h_hist[CHUNK - 1][tid] = 0.0f;  // h(-1) = 0 lives in slot CHUNK-1

    // ---- W_fc columns for this lane (used in FC flush) ----
    float wfc0[OUTD], wfc1[OUTD], bfc[OUTD];
    #pragma unroll
    for (int o = 0; o < OUTD; ++o) {
        wfc0[o] = W_fc[o * HID + 2 * lane];
        wfc1[o] = W_fc[o * HID + 2 * lane + 1];
        bfc[o]  = b_fc[o];
    }

    for (int ch = 0; ch < NCHUNK; ++ch) {
        const int t0 = ch * CHUNK;
        if (tid < CHUNK) toks[tid] = inputs[(size_t)b * TT + t0 + tid];
        __syncthreads();

        for (int s = 0; s < CHUNK; ++s) {
            const int prev = (s + CHUNK - 1) & (CHUNK - 1);
            const int tok  = toks[s];
            const float xg = gtab[tok][g];

            float p0 = 0.f, p1 = 0.f, p2 = 0.f, p3 = 0.f;
            const float4* hp = (const float4*)&h_hist[prev][0]; // uniform addr -> LDS broadcast
            #pragma unroll
            for (int k = 0; k < HID / 4; ++k) {
                float4 hv = hp[k];
                p0 += w[4 * k + 0] * hv.x;
                p1 += w[4 * k + 1] * hv.y;
                p2 += w[4 * k + 2] * hv.z;
                p3 += w[4 * k + 3] * hv.w;
            }
            float pre = (p0 + p1) + (p2 + p3) + xg;

            // group: waves 0-3 -> i,f (sigmoid); 4,5 -> g (tanh); 6,7 -> o (sigmoid). Wave-uniform branch.
            float act = (g < 2 * HID || g >= 3 * HID) ? sigmoid_f(pre) : tanh_f(pre);
            gact[g] = act;
            __syncthreads();

            // c/h update, replicated across the 4 gate groups (identical values; benign same-addr write)
            {
                float gi = gact[j];
                float gf = gact[HID + j];
                float gg = gact[2 * HID + j];
                float go = gact[3 * HID + j];
                c = gf * c + gi * gg;
                float h = go * tanh_f(c);
                h_hist[s][j] = h;
            }
            __syncthreads();
        }

        // ---- FC + softmax flush for steps t0 .. t0+CHUNK-1 ----
        #pragma unroll 1
        for (int i = 0; i < CHUNK / 8; ++i) {
            const int r = wave * (CHUNK / 8) + i;   // row (timestep) in chunk
            float2 hv = *(const float2*)&h_hist[r][2 * lane];
            float acc[OUTD];
            #pragma unroll
            for (int o = 0; o < OUTD; ++o) acc[o] = wfc0[o] * hv.x + wfc1[o] * hv.y;
            #pragma unroll
            for (int off = 32; off >= 1; off >>= 1) {
                #pragma unroll
                for (int o = 0; o < OUTD; ++o) acc[o] += __shfl_xor(acc[o], off, 64);
            }
            if (lane == 0) {
                float m = -1e30f;
                #pragma unroll
                for (int o = 0; o < OUTD; ++o) { acc[o] += bfc[o]; m = fmaxf(m, acc[o]); }
                float e[OUTD], ssum = 0.f;
                #pragma unroll
                for (int o = 0; o < OUTD; ++o) { e[o] = v_exp2(1.44269504f * (acc[o] - m)); ssum += e[o]; }
                float inv = v_rcp(ssum);
                float* po = out + ((size_t)b * TT + (t0 + r)) * OUTD;
                #pragma unroll
                for (int o = 0; o < OUTD; ++o) po[o] = e[o] * inv;
            }
        }
        __syncthreads();
    }
}

extern "C" void kernel_launch(void* const* d_in, const int* in_sizes, int n_in,
                              void* d_out, int out_size, void* d_ws, size_t ws_size,
                              hipStream_t stream) {
    const int*   inputs = (const int*)  d_in[0];
    const float* c0     = (const float*)d_in[1];
    const float* W_ih   = (const float*)d_in[2];
    const float* W_hh   = (const float*)d_in[3];
    const float* b_ih   = (const float*)d_in[4];
    const float* b_hh   = (const float*)d_in[5];
    const float* W_fc   = (const float*)d_in[6];
    const float* b_fc   = (const float*)d_in[7];
    const float* emb    = (const float*)d_in[8];
    float* out = (float*)d_out;

    lstm_persist<<<BB, 512, 0, stream>>>(inputs, c0, W_ih, W_hh, b_ih, b_hh,
                                         W_fc, b_fc, emb, out);
}

// Round 2
// 2015.415 us; speedup vs baseline: 1.0147x; 1.0147x over previous
//
#include <hip/hip_runtime.h>
#include <math.h>

#define BB 256
#define TT 2048
#define VOCAB 7
#define EMBD 20
#define HID 128
#define OUTD 6
#define CHUNK 64
#define NCHUNK (TT / CHUNK)
#define SLICE 32       // h columns per thread
#define SPAD 36        // padded slice stride (floats): slice bases on banks 0,4,8,12

// Single-instruction fast ops (gfx950, ~1 ULP)
__device__ __forceinline__ float v_exp2(float x) {
    float r; asm("v_exp_f32 %0, %1" : "=v"(r) : "v"(x)); return r;
}
__device__ __forceinline__ float v_rcp(float x) {
    float r; asm("v_rcp_f32 %0, %1" : "=v"(r) : "v"(x)); return r;
}
__device__ __forceinline__ float sigmoid_f(float x) {
    return v_rcp(1.0f + v_exp2(-1.44269504f * x));
}
__device__ __forceinline__ float tanh_f(float x) {
    float ax = fabsf(x);
    float t = v_exp2(-2.88539008f * ax);          // exp(-2|x|)
    float r = (1.0f - t) * v_rcp(1.0f + t);
    return __builtin_copysignf(r, x);
}

// Pin a value into a VGPR: rematerializing the original load past this is illegal.
#define KEEP(x) asm volatile("" : "+v"(x))

// One block per batch element, persistent over all T steps.
// Thread (j,q) = (tid>>2, tid&3) owns unit j, h-slice [32q, 32q+32):
// it holds W_hh[{i,f,g,o} row of unit j][32q:32q+32] in 128 VGPRs.
__global__ __launch_bounds__(512) __attribute__((amdgpu_waves_per_eu(2, 2)))
void lstm_persist(
    const int* __restrict__ inputs, const float* __restrict__ c0,
    const float* __restrict__ W_ih, const float* __restrict__ W_hh,
    const float* __restrict__ b_ih, const float* __restrict__ b_hh,
    const float* __restrict__ W_fc, const float* __restrict__ b_fc,
    const float* __restrict__ emb, float* __restrict__ out)
{
    __shared__ float gtab[VOCAB][HID][4];   // [tok][unit][gate i,f,g,o] = 14336 B
    __shared__ float hbuf[CHUNK][4][SPAD];  // padded h ring buffer = 36864 B
    __shared__ int   toks[CHUNK];           // 256 B

    const int tid  = threadIdx.x;
    const int b    = blockIdx.x;
    const int j    = tid >> 2;      // hidden unit 0..127
    const int q    = tid & 3;       // h slice 0..3
    const int lane = tid & 63;
    const int wave = tid >> 6;

    // ---- W_hh rows {i,f,g,o} of unit j, columns [32q, 32q+32) -> 128 VGPRs ----
    float w[4][SLICE];
    #pragma unroll
    for (int r = 0; r < 4; ++r) {
        const float4* wr = (const float4*)(W_hh + ((size_t)(r * HID + j) * HID + q * SLICE));
        #pragma unroll
        for (int k = 0; k < SLICE / 4; ++k) {
            float4 v = wr[k];
            w[r][4 * k + 0] = v.x; w[r][4 * k + 1] = v.y;
            w[r][4 * k + 2] = v.z; w[r][4 * k + 3] = v.w;
        }
    }
    #pragma unroll
    for (int r = 0; r < 4; ++r)
        #pragma unroll
        for (int k = 0; k < SLICE; ++k) KEEP(w[r][k]);

    // ---- token -> gate preact table: gtab[v][unit][gate] = W_ih[g,:]·emb[v,:]+b_ih[g]+b_hh[g]
    {
        const int g = tid;                      // old row id: gate = g>>7, unit = g&127
        float wih[EMBD];
        #pragma unroll
        for (int e = 0; e < EMBD; ++e) wih[e] = W_ih[g * EMBD + e];
        float bb = b_ih[g] + b_hh[g];
        #pragma unroll
        for (int v = 0; v < VOCAB; ++v) {
            float a = bb;
            #pragma unroll
            for (int e = 0; e < EMBD; ++e) a += wih[e] * emb[v * EMBD + e];
            gtab[v][g & (HID - 1)][g >> 7] = a;
        }
    }

    // ---- state ----
    float c = c0[b * HID + j];                  // replicated across the 4 q-slices
    if (tid < 4 * SPAD) ((float*)hbuf[CHUNK - 1])[tid] = 0.0f;  // h(-1) = 0

    // ---- W_fc columns for this lane (FC flush) ----
    float wfc0[OUTD], wfc1[OUTD], bfc[OUTD];
    #pragma unroll
    for (int o = 0; o < OUTD; ++o) {
        wfc0[o] = W_fc[o * HID + 2 * lane];
        wfc1[o] = W_fc[o * HID + 2 * lane + 1];
        bfc[o]  = b_fc[o];
    }
    __syncthreads();

    #pragma unroll 1
    for (int ch = 0; ch < NCHUNK; ++ch) {
        const int t0 = ch * CHUNK;
        if (tid < CHUNK) toks[tid] = inputs[(size_t)b * TT + t0 + tid];
        __syncthreads();

        #pragma unroll 1
        for (int s = 0; s < CHUNK; ++s) {
            const int prev = (s + CHUNK - 1) & (CHUNK - 1);
            const int tok  = toks[s];
            // h slice read: 8 ds_read_b128, slice bases on distinct bank groups
            const float4* hp = (const float4*)&hbuf[prev][q][0];
            float ai = 0.f, af = 0.f, ag = 0.f, ao = 0.f;
            #pragma unroll
            for (int k = 0; k < SLICE / 4; ++k) {
                float4 hv = hp[k];
                ai += w[0][4*k+0]*hv.x + w[0][4*k+1]*hv.y + w[0][4*k+2]*hv.z + w[0][4*k+3]*hv.w;
                af += w[1][4*k+0]*hv.x + w[1][4*k+1]*hv.y + w[1][4*k+2]*hv.z + w[1][4*k+3]*hv.w;
                ag += w[2][4*k+0]*hv.x + w[2][4*k+1]*hv.y + w[2][4*k+2]*hv.z + w[2][4*k+3]*hv.w;
                ao += w[3][4*k+0]*hv.x + w[3][4*k+1]*hv.y + w[3][4*k+2]*hv.z + w[3][4*k+3]*hv.w;
            }
            // reduce the 4 q-partials (4-lane groups, DPP quad-perm)
            ai += __shfl_xor(ai, 1, 64); ai += __shfl_xor(ai, 2, 64);
            af += __shfl_xor(af, 1, 64); af += __shfl_xor(af, 2, 64);
            ag += __shfl_xor(ag, 1, 64); ag += __shfl_xor(ag, 2, 64);
            ao += __shfl_xor(ao, 1, 64); ao += __shfl_xor(ao, 2, 64);

            const float4 xg = *(const float4*)&gtab[tok][j][0];
            float gi = sigmoid_f(ai + xg.x);
            float gf = sigmoid_f(af + xg.y);
            float gg = tanh_f  (ag + xg.z);
            float go = sigmoid_f(ao + xg.w);
            c = gf * c + gi * gg;
            float h = go * tanh_f(c);
            if (q == 0) hbuf[s][j >> 5][j & 31] = h;   // one writer per unit
            __syncthreads();
        }

        // ---- FC + softmax flush for this chunk ----
        #pragma unroll 1
        for (int i = 0; i < CHUNK / 8; ++i) {
            const int r = wave * (CHUNK / 8) + i;     // timestep row in chunk
            const float2 hv = *(const float2*)&hbuf[r][lane >> 4][(2 * lane) & 31];
            float acc[OUTD];
            #pragma unroll
            for (int o = 0; o < OUTD; ++o) acc[o] = wfc0[o] * hv.x + wfc1[o] * hv.y;
            #pragma unroll
            for (int off = 32; off >= 1; off >>= 1) {
                #pragma unroll
                for (int o = 0; o < OUTD; ++o) acc[o] += __shfl_xor(acc[o], off, 64);
            }
            if (lane == 0) {
                float m = -1e30f;
                #pragma unroll
                for (int o = 0; o < OUTD; ++o) { acc[o] += bfc[o]; m = fmaxf(m, acc[o]); }
                float e[OUTD], ssum = 0.f;
                #pragma unroll
                for (int o = 0; o < OUTD; ++o) { e[o] = v_exp2(1.44269504f * (acc[o] - m)); ssum += e[o]; }
                float inv = v_rcp(ssum);
                float* po = out + ((size_t)b * TT + (t0 + r)) * OUTD;
                #pragma unroll
                for (int o = 0; o < OUTD; ++o) po[o] = e[o] * inv;
            }
        }
        __syncthreads();
    }
}

extern "C" void kernel_launch(void* const* d_in, const int* in_sizes, int n_in,
                              void* d_out, int out_size, void* d_ws, size_t ws_size,
                              hipStream_t stream) {
    const int*   inputs = (const int*)  d_in[0];
    const float* c0     = (const float*)d_in[1];
    const float* W_ih   = (const float*)d_in[2];
    const float* W_hh   = (const float*)d_in[3];
    const float* b_ih   = (const float*)d_in[4];
    const float* b_hh   = (const float*)d_in[5];
    const float* W_fc   = (const float*)d_in[6];
    const float* b_fc   = (const float*)d_in[7];
    const float* emb    = (const float*)d_in[8];
    float* out = (float*)d_out;

    lstm_persist<<<BB, 512, 0, stream>>>(inputs, c0, W_ih, W_hh, b_ih, b_hh,
                                         W_fc, b_fc, emb, out);
}

// Round 4
// 1606.215 us; speedup vs baseline: 1.2733x; 1.2548x over previous
//
#include <hip/hip_runtime.h>
#include <math.h>

#define BB 256
#define TT 2048
#define VOCAB 7
#define EMBD 20
#define HID 128
#define OUTD 6
#define CHUNK 64
#define NCHUNK (TT / CHUNK)

typedef _Float16 h2 __attribute__((ext_vector_type(2)));

// Single-instruction fast ops (gfx950, ~1 ULP)
__device__ __forceinline__ float v_exp2(float x) {
    float r; asm("v_exp_f32 %0, %1" : "=v"(r) : "v"(x)); return r;
}
__device__ __forceinline__ float v_rcp(float x) {
    float r; asm("v_rcp_f32 %0, %1" : "=v"(r) : "v"(x)); return r;
}
__device__ __forceinline__ float sigmoid_f(float x) {
    return v_rcp(1.0f + v_exp2(-1.44269504f * x));
}
__device__ __forceinline__ float tanh_f(float x) {
    float ax = fabsf(x);
    float t = v_exp2(-2.88539008f * ax);          // exp(-2|x|)
    float r = (1.0f - t) * v_rcp(1.0f + t);
    return __builtin_copysignf(r, x);
}

#if defined(__has_builtin)
#if __has_builtin(__builtin_amdgcn_fdot2)
#define HAS_FDOT2 1
#endif
#endif

// d = a.x*b.x + a.y*b.y + c with f32 accumulate (v_dot2_f32_f16)
__device__ __forceinline__ float dot2acc(h2 a, h2 b, float c) {
#ifdef HAS_FDOT2
    return __builtin_amdgcn_fdot2(a, b, c, false);
#else
    return c + (float)a.x * (float)b.x + (float)a.y * (float)b.y;
#endif
}

#define KEEP(x) asm volatile("" : "+v"(x))

// One block per batch element, persistent over all T steps.
// Thread (j,r) = (tid>>2, tid&3): computes gate r (i,f,g,o) of unit j.
// Holds W_hh row (r*128+j) as 64 packed f16 pairs in 64 VGPRs.
__global__ __launch_bounds__(512, 2) void lstm_persist(
    const int* __restrict__ inputs, const float* __restrict__ c0,
    const float* __restrict__ W_ih, const float* __restrict__ W_hh,
    const float* __restrict__ b_ih, const float* __restrict__ b_hh,
    const float* __restrict__ W_fc, const float* __restrict__ b_fc,
    const float* __restrict__ emb, float* __restrict__ out)
{
    __shared__ float gtab[VOCAB][4 * HID];  // [tok][tid] gate preact, 14 KB
    __shared__ h2    hbuf[CHUNK][HID / 2];  // h ring buffer in f16, 16 KB
    __shared__ int   toks[CHUNK];           // 256 B

    const int tid  = threadIdx.x;
    const int b    = blockIdx.x;
    const int j    = tid >> 2;      // hidden unit 0..127
    const int r    = tid & 3;       // gate 0..3 (i,f,g,o)
    const int lane = tid & 63;
    const int wave = tid >> 6;

    // ---- W_hh row (gate r of unit j) -> 64 f16 pairs in VGPRs ----
    h2 w[HID / 2];
    {
        const float2* wr = (const float2*)(W_hh + (size_t)(r * HID + j) * HID);
        #pragma unroll
        for (int k = 0; k < HID / 2; ++k) {
            float2 f = wr[k];
            h2 p; p.x = (_Float16)f.x; p.y = (_Float16)f.y;
            w[k] = p;
        }
    }
    #pragma unroll
    for (int k = 0; k < HID / 2; ++k) KEEP(w[k]);

    // ---- token -> gate preact table: gtab[v][tid] = W_ih[g,:]·emb[v,:] + b_ih[g] + b_hh[g]
    {
        const int g = r * HID + j;
        float wih[EMBD];
        #pragma unroll
        for (int e = 0; e < EMBD; ++e) wih[e] = W_ih[g * EMBD + e];
        float bb = b_ih[g] + b_hh[g];
        #pragma unroll
        for (int v = 0; v < VOCAB; ++v) {
            float a = bb;
            #pragma unroll
            for (int e = 0; e < EMBD; ++e) a += wih[e] * emb[v * EMBD + e];
            gtab[v][tid] = a;
        }
    }

    // ---- state ----
    float c = c0[b * HID + j];      // replicated across the 4 gate lanes of unit j
    if (tid < HID / 2) {            // h(-1) = 0 lives in slot CHUNK-1
        h2 z; z.x = (_Float16)0.f; z.y = (_Float16)0.f;
        hbuf[CHUNK - 1][tid] = z;
    }
    __syncthreads();

    #pragma unroll 1
    for (int ch = 0; ch < NCHUNK; ++ch) {
        const int t0 = ch * CHUNK;
        if (tid < CHUNK) toks[tid] = inputs[(size_t)b * TT + t0 + tid];
        __syncthreads();

        #pragma unroll 1
        for (int s = 0; s < CHUNK; ++s) {
            const int prev = (s + CHUNK - 1) & (CHUNK - 1);
            const float xg = gtab[toks[s]][tid];

            // full h dot: 16 broadcast ds_read_b128 (uniform addr), 64 v_dot2
            const uint4* hp = (const uint4*)&hbuf[prev][0];
            float a0 = 0.f, a1 = 0.f, a2 = 0.f, a3 = 0.f;
            #pragma unroll
            for (int k = 0; k < 16; ++k) {
                uint4 v = hp[k];
                a0 = dot2acc(w[4 * k + 0], __builtin_bit_cast(h2, v.x), a0);
                a1 = dot2acc(w[4 * k + 1], __builtin_bit_cast(h2, v.y), a1);
                a2 = dot2acc(w[4 * k + 2], __builtin_bit_cast(h2, v.z), a2);
                a3 = dot2acc(w[4 * k + 3], __builtin_bit_cast(h2, v.w), a3);
            }
            float pre = (a0 + a1) + (a2 + a3) + xg;

            // activation for my gate; gate g (r==2) is tanh, others sigmoid
            float act = (r == 2) ? tanh_f(pre) : sigmoid_f(pre);

            // exchange within the 4-lane quad: x[k] = act of gate (r^k)
            float x1 = __shfl_xor(act, 1, 64);
            float x2 = __shfl_xor(act, 2, 64);
            float x3 = __shfl_xor(act, 3, 64);
            const bool b1 = (r & 1), b2 = (r & 2) != 0;
            float gi = b2 ? (b1 ? x3 : x2) : (b1 ? x1 : act);   // x[r^0]
            float gf = b2 ? (b1 ? x2 : x3) : (b1 ? act : x1);   // x[r^1]
            float gg = b2 ? (b1 ? x1 : act) : (b1 ? x3 : x2);   // x[r^2]
            float go = b2 ? (b1 ? act : x1) : (b1 ? x2 : x3);   // x[r^3]

            c = gf * c + gi * gg;                // replicated x4, identical values
            float h = go * tanh_f(c);
            if (r == 0) ((_Float16*)&hbuf[s][0])[j] = (_Float16)h;
            __syncthreads();
        }

        // ---- FC + softmax flush for this chunk ----
        {
            float wfc0[OUTD], wfc1[OUTD];
            #pragma unroll
            for (int o = 0; o < OUTD; ++o) {
                wfc0[o] = W_fc[o * HID + 2 * lane];
                wfc1[o] = W_fc[o * HID + 2 * lane + 1];
            }
            #pragma unroll 1
            for (int i = 0; i < CHUNK / 8; ++i) {
                const int row = wave * (CHUNK / 8) + i;   // timestep row in chunk
                h2 hv = hbuf[row][lane];
                float h0 = (float)hv.x, h1 = (float)hv.y;
                float acc[OUTD];
                #pragma unroll
                for (int o = 0; o < OUTD; ++o) acc[o] = wfc0[o] * h0 + wfc1[o] * h1;
                #pragma unroll
                for (int off = 32; off >= 1; off >>= 1) {
                    #pragma unroll
                    for (int o = 0; o < OUTD; ++o) acc[o] += __shfl_xor(acc[o], off, 64);
                }
                if (lane == 0) {
                    float m = -1e30f;
                    #pragma unroll
                    for (int o = 0; o < OUTD; ++o) { acc[o] += b_fc[o]; m = fmaxf(m, acc[o]); }
                    float e[OUTD], ssum = 0.f;
                    #pragma unroll
                    for (int o = 0; o < OUTD; ++o) { e[o] = v_exp2(1.44269504f * (acc[o] - m)); ssum += e[o]; }
                    float inv = v_rcp(ssum);
                    float* po = out + ((size_t)b * TT + (t0 + row)) * OUTD;
                    #pragma unroll
                    for (int o = 0; o < OUTD; ++o) po[o] = e[o] * inv;
                }
            }
        }
        __syncthreads();
    }
}

extern "C" void kernel_launch(void* const* d_in, const int* in_sizes, int n_in,
                              void* d_out, int out_size, void* d_ws, size_t ws_size,
                              hipStream_t stream) {
    const int*   inputs = (const int*)  d_in[0];
    const float* c0     = (const float*)d_in[1];
    const float* W_ih   = (const float*)d_in[2];
    const float* W_hh   = (const float*)d_in[3];
    const float* b_ih   = (const float*)d_in[4];
    const float* b_hh   = (const float*)d_in[5];
    const float* W_fc   = (const float*)d_in[6];
    const float* b_fc   = (const float*)d_in[7];
    const float* emb    = (const float*)d_in[8];
    float* out = (float*)d_out;

    lstm_persist<<<BB, 512, 0, stream>>>(inputs, c0, W_ih, W_hh, b_ih, b_hh,
                                         W_fc, b_fc, emb, out);
}

// Round 6
// 1570.378 us; speedup vs baseline: 1.3023x; 1.0228x over previous
//
#include <hip/hip_runtime.h>
#include <math.h>

#define BB 256
#define TT 2048
#define VOCAB 7
#define EMBD 20
#define HID 128
#define OUTD 6
#define CHUNK 64
#define NCHUNK (TT / CHUNK)

typedef _Float16 h2 __attribute__((ext_vector_type(2)));

// Single-instruction fast ops (gfx950, ~1 ULP)
__device__ __forceinline__ float v_exp2(float x) {
    float r; asm("v_exp_f32 %0, %1" : "=v"(r) : "v"(x)); return r;
}
__device__ __forceinline__ float v_rcp(float x) {
    float r; asm("v_rcp_f32 %0, %1" : "=v"(r) : "v"(x)); return r;
}
__device__ __forceinline__ float sigmoid_f(float x) {
    return v_rcp(1.0f + v_exp2(-1.44269504f * x));
}
__device__ __forceinline__ float tanh_f(float x) {
    float ax = fabsf(x);
    float t = v_exp2(-2.88539008f * ax);          // exp(-2|x|)
    float r = (1.0f - t) * v_rcp(1.0f + t);
    return __builtin_copysignf(r, x);
}

// Guaranteed v_dot2_f32_f16 emission (f32 accumulate)
__device__ __forceinline__ float dot2(h2 a, h2 b, float c) {
    float d;
    asm("v_dot2_f32_f16 %0, %1, %2, %3" : "=v"(d) : "v"(a), "v"(b), "v"(c));
    return d;
}

#define KEEP(x) asm volatile("" : "+v"(x))

// One block per batch element (grid == 256 == #CUs), persistent over all T.
// Thread (j,r) = (tid>>2, tid&3): ALL 4 gates of unit j over h-slice [32r,32r+32).
// Weights: 4 gates x 16 h2 pairs = 64 VGPRs.
__global__ __launch_bounds__(512) void lstm_persist(
    const int* __restrict__ inputs, const float* __restrict__ c0,
    const float* __restrict__ W_ih, const float* __restrict__ W_hh,
    const float* __restrict__ b_ih, const float* __restrict__ b_hh,
    const float* __restrict__ W_fc, const float* __restrict__ b_fc,
    const float* __restrict__ emb, float* __restrict__ out)
{
    __shared__ float4   gtab[VOCAB][HID];     // per-token gate preacts (i,f,g,o) 14 KB
    __shared__ _Float16 hbuf[CHUNK][HID];     // h ring buffer, f16, 16 KB
    __shared__ int      toks[CHUNK];          // 256 B
    // Occupancy shaper: 126 KB static LDS -> 1 block/CU -> 2 waves/SIMD ->
    // register allocator budget 256 VGPRs (we really do run 1 block/CU: grid=256).
    __shared__ char     ldspad[96 * 1024];

    const int tid  = threadIdx.x;
    const int b    = blockIdx.x;
    const int j    = tid >> 2;      // hidden unit 0..127
    const int r    = tid & 3;       // h slice 0..3
    const int lane = tid & 63;
    const int wave = tid >> 6;

    // keep ldspad alive: data-dependent, never-true (tokens are 0..6)
    if (__builtin_expect(inputs[0] == -2147483647, 0)) ldspad[tid] = 1;

    // ---- W_hh: gates 0..3 of unit j, h columns [32r, 32r+32) -> 64 h2 VGPRs ----
    h2 w0[16], w1[16], w2[16], w3[16];
    {
        const float2* p0 = (const float2*)(W_hh + ((size_t)(0 * HID + j) * HID + r * 32));
        const float2* p1 = (const float2*)(W_hh + ((size_t)(1 * HID + j) * HID + r * 32));
        const float2* p2 = (const float2*)(W_hh + ((size_t)(2 * HID + j) * HID + r * 32));
        const float2* p3 = (const float2*)(W_hh + ((size_t)(3 * HID + j) * HID + r * 32));
        #pragma unroll
        for (int k = 0; k < 16; ++k) {
            float2 f0 = p0[k], f1 = p1[k], f2 = p2[k], f3 = p3[k];
            h2 a; a.x = (_Float16)f0.x; a.y = (_Float16)f0.y; w0[k] = a;
            h2 bq; bq.x = (_Float16)f1.x; bq.y = (_Float16)f1.y; w1[k] = bq;
            h2 cq; cq.x = (_Float16)f2.x; cq.y = (_Float16)f2.y; w2[k] = cq;
            h2 dq; dq.x = (_Float16)f3.x; dq.y = (_Float16)f3.y; w3[k] = dq;
        }
    }
    #pragma unroll
    for (int k = 0; k < 16; ++k) { KEEP(w0[k]); KEEP(w1[k]); KEEP(w2[k]); KEEP(w3[k]); }

    // ---- token -> gate preact table: gtab[v][j][gate r] (thread builds row g=r*128+j)
    {
        const int g = r * HID + j;
        float wih[EMBD];
        #pragma unroll
        for (int e = 0; e < EMBD; ++e) wih[e] = W_ih[g * EMBD + e];
        float bb = b_ih[g] + b_hh[g];
        #pragma unroll
        for (int v = 0; v < VOCAB; ++v) {
            float a = bb;
            #pragma unroll
            for (int e = 0; e < EMBD; ++e) a += wih[e] * emb[v * EMBD + e];
            ((float*)&gtab[v][j])[r] = a;
        }
    }

    // ---- state ----
    float c = c0[b * HID + j];      // replicated across the 4 slice lanes of unit j
    if (tid < HID) hbuf[CHUNK - 1][tid] = (_Float16)0.f;   // h(-1)=0 in slot CHUNK-1

    // ---- FC weights hoisted (lane-sliced columns) ----
    float wfc0[OUTD], wfc1[OUTD], bfc[OUTD];
    #pragma unroll
    for (int o = 0; o < OUTD; ++o) {
        wfc0[o] = W_fc[o * HID + 2 * lane];
        wfc1[o] = W_fc[o * HID + 2 * lane + 1];
        bfc[o]  = b_fc[o];
    }
    __syncthreads();

    #pragma unroll 1
    for (int ch = 0; ch < NCHUNK; ++ch) {
        const int t0 = ch * CHUNK;
        if (tid < CHUNK) toks[tid] = inputs[(size_t)b * TT + t0 + tid];
        __syncthreads();

        #pragma unroll 1
        for (int s = 0; s < CHUNK; ++s) {
            const int prev = (s + CHUNK - 1) & (CHUNK - 1);

            // h slice read: 4 ds_read_b128 (4 distinct lines/wave, 2-way bank alias = free)
            const uint4* hp = (const uint4*)&hbuf[prev][r * 32];
            float a0 = 0.f, a1 = 0.f, a2 = 0.f, a3 = 0.f;
            #pragma unroll
            for (int k = 0; k < 4; ++k) {
                uint4 v = hp[k];
                h2 hx = __builtin_bit_cast(h2, v.x);
                h2 hy = __builtin_bit_cast(h2, v.y);
                h2 hz = __builtin_bit_cast(h2, v.z);
                h2 hw = __builtin_bit_cast(h2, v.w);
                a0 = dot2(w0[4*k+0], hx, a0); a0 = dot2(w0[4*k+1], hy, a0);
                a0 = dot2(w0[4*k+2], hz, a0); a0 = dot2(w0[4*k+3], hw, a0);
                a1 = dot2(w1[4*k+0], hx, a1); a1 = dot2(w1[4*k+1], hy, a1);
                a1 = dot2(w1[4*k+2], hz, a1); a1 = dot2(w1[4*k+3], hw, a1);
                a2 = dot2(w2[4*k+0], hx, a2); a2 = dot2(w2[4*k+1], hy, a2);
                a2 = dot2(w2[4*k+2], hz, a2); a2 = dot2(w2[4*k+3], hw, a2);
                a3 = dot2(w3[4*k+0], hx, a3); a3 = dot2(w3[4*k+1], hy, a3);
                a3 = dot2(w3[4*k+2], hz, a3); a3 = dot2(w3[4*k+3], hw, a3);
            }
            // quad reduce over the 4 h-slices -> every quad lane gets full 4 gate sums
            a0 += __shfl_xor(a0, 1, 64); a0 += __shfl_xor(a0, 2, 64);
            a1 += __shfl_xor(a1, 1, 64); a1 += __shfl_xor(a1, 2, 64);
            a2 += __shfl_xor(a2, 1, 64); a2 += __shfl_xor(a2, 2, 64);
            a3 += __shfl_xor(a3, 1, 64); a3 += __shfl_xor(a3, 2, 64);

            const float4 xg = gtab[toks[s]][j];   // quad-uniform b128
            float gi = sigmoid_f(a0 + xg.x);
            float gf = sigmoid_f(a1 + xg.y);
            float gg = tanh_f  (a2 + xg.z);
            float go = sigmoid_f(a3 + xg.w);
            c = gf * c + gi * gg;                 // replicated x4, identical values
            float h = go * tanh_f(c);
            if (r == 0) hbuf[s][j] = (_Float16)h;
            __syncthreads();
        }

        // ---- FC + softmax flush for this chunk ----
        #pragma unroll 1
        for (int i = 0; i < CHUNK / 8; ++i) {
            const int row = wave * (CHUNK / 8) + i;   // timestep row in chunk
            h2 hv = ((const h2*)&hbuf[row][0])[lane];
            float h0 = (float)hv.x, h1 = (float)hv.y;
            float acc[OUTD];
            #pragma unroll
            for (int o = 0; o < OUTD; ++o) acc[o] = wfc0[o] * h0 + wfc1[o] * h1;
            #pragma unroll
            for (int off = 32; off >= 1; off >>= 1) {
                #pragma unroll
                for (int o = 0; o < OUTD; ++o) acc[o] += __shfl_xor(acc[o], off, 64);
            }
            if (lane == 0) {
                float m = -1e30f;
                #pragma unroll
                for (int o = 0; o < OUTD; ++o) { acc[o] += bfc[o]; m = fmaxf(m, acc[o]); }
                float e[OUTD], ssum = 0.f;
                #pragma unroll
                for (int o = 0; o < OUTD; ++o) { e[o] = v_exp2(1.44269504f * (acc[o] - m)); ssum += e[o]; }
                float inv = v_rcp(ssum);
                float* po = out + ((size_t)b * TT + (t0 + row)) * OUTD;
                #pragma unroll
                for (int o = 0; o < OUTD; ++o) po[o] = e[o] * inv;
            }
        }
        __syncthreads();
    }
}

extern "C" void kernel_launch(void* const* d_in, const int* in_sizes, int n_in,
                              void* d_out, int out_size, void* d_ws, size_t ws_size,
                              hipStream_t stream) {
    const int*   inputs = (const int*)  d_in[0];
    const float* c0     = (const float*)d_in[1];
    const float* W_ih   = (const float*)d_in[2];
    const float* W_hh   = (const float*)d_in[3];
    const float* b_ih   = (const float*)d_in[4];
    const float* b_hh   = (const float*)d_in[5];
    const float* W_fc   = (const float*)d_in[6];
    const float* b_fc   = (const float*)d_in[7];
    const float* emb    = (const float*)d_in[8];
    float* out = (float*)d_out;

    lstm_persist<<<BB, 512, 0, stream>>>(inputs, c0, W_ih, W_hh, b_ih, b_hh,
                                         W_fc, b_fc, emb, out);
}